// Round 1
// baseline (441.033 us; speedup 1.0000x reference)
//
#include <hip/hip_runtime.h>
#include <math.h>

// Problem: TripletAttention. x:[32,256,56,56] f32.
// out[b,c,h,w] = x * (s1[b,c,w] + s2[b,h,c] + s3[b,h,w]) / 3
// s1 = sig(BN0(conv7x7(zpool_h(x))))  over spatial (c,w)
// s2 = sig(BN1(conv7x7(zpool_w(x))))  over spatial (h,c)
// s3 = sig(BN2(conv7x7(zpool_c(x))))  over spatial (h,w)

#define B_ 32
#define C_ 256
#define H_ 56
#define W_ 56
#define HW_ 3136          // 56*56
#define CK 16             // planes per pool block
#define NCHUNK (C_ / CK)  // 16

// ---------------- Kernel A: pool over h (P1), over w (P2), partial pool over c (P3p) --------
// grid: B_*NCHUNK blocks, 256 threads. One block streams CK (b,c) planes via LDS.
__global__ __launch_bounds__(256) void pool_kernel(const float* __restrict__ x,
                                                   float* __restrict__ P1,   // [B][2][C][W]
                                                   float* __restrict__ P2,   // [B][2][H][C]
                                                   float* __restrict__ P3p)  // [B][NCHUNK][2][HW]
{
    __shared__ float plane[H_ * 57];  // pad stride 57 (coprime with 32 banks)
    const int t = threadIdx.x;
    const int lane = t & 63;
    const int wv = t >> 6;  // wave 0..3
    const int bid = blockIdx.x;
    const int b = bid >> 4;       // / NCHUNK
    const int chunk = bid & 15;   // % NCHUNK
    const int c0 = chunk * CK;

    float p3max[13], p3sum[13];
#pragma unroll
    for (int i = 0; i < 13; ++i) { p3max[i] = -INFINITY; p3sum[i] = 0.f; }

    for (int cc = 0; cc < CK; ++cc) {
        const int c = c0 + cc;
        const float* src = x + ((size_t)(b * C_ + c)) * HW_;

        // stage plane -> LDS (13 independent loads in flight, then LDS writes)
        float vreg[13];
#pragma unroll
        for (int i = 0; i < 13; ++i) {
            int g = t + i * 256;
            int gc = g < HW_ ? g : (HW_ - 1);
            vreg[i] = src[gc];
        }
#pragma unroll
        for (int i = 0; i < 13; ++i) {
            int g = t + i * 256;
            if (g < HW_) {
                int h = g / 56;
                int w = g - h * 56;
                plane[h * 57 + w] = vreg[i];
            }
        }
        __syncthreads();

        // rows: reduce over w -> P2[b][.][h][c]
        for (int h = wv; h < H_; h += 4) {
            float v = (lane < W_) ? plane[h * 57 + lane] : -INFINITY;
            float s = (lane < W_) ? v : 0.f;
#pragma unroll
            for (int off = 32; off > 0; off >>= 1) {
                v = fmaxf(v, __shfl_down(v, off));
                s += __shfl_down(s, off);
            }
            if (lane == 0) {
                P2[(((size_t)b * 2 + 0) * H_ + h) * C_ + c] = v;
                P2[(((size_t)b * 2 + 1) * H_ + h) * C_ + c] = s * (1.f / 56.f);
            }
        }
        // cols: reduce over h -> P1[b][.][c][w]   (stride-57 LDS reads: conflict-free)
        for (int w = wv; w < W_; w += 4) {
            float v = (lane < H_) ? plane[lane * 57 + w] : -INFINITY;
            float s = (lane < H_) ? v : 0.f;
#pragma unroll
            for (int off = 32; off > 0; off >>= 1) {
                v = fmaxf(v, __shfl_down(v, off));
                s += __shfl_down(s, off);
            }
            if (lane == 0) {
                P1[(((size_t)b * 2 + 0) * C_ + c) * W_ + w] = v;
                P1[(((size_t)b * 2 + 1) * C_ + c) * W_ + w] = s * (1.f / 56.f);
            }
        }
        // partial pool over c
        {
            int i = 0;
            for (int g = t; g < HW_; g += 256, ++i) {
                int h = g / 56;
                int w = g - h * 56;
                float v = plane[h * 57 + w];
                p3max[i] = fmaxf(p3max[i], v);
                p3sum[i] += v;
            }
        }
        __syncthreads();
    }

    {
        int i = 0;
        for (int g = t; g < HW_; g += 256, ++i) {
            P3p[(((size_t)(b * NCHUNK + chunk)) * 2 + 0) * HW_ + g] = p3max[i];
            P3p[(((size_t)(b * NCHUNK + chunk)) * 2 + 1) * HW_ + g] = p3sum[i];
        }
    }
}

// ---------------- Kernel B: reduce chunk partials -> P3[b][2][HW] ----------------
__global__ __launch_bounds__(256) void p3_reduce(const float* __restrict__ P3p,
                                                 float* __restrict__ P3) {
    int id = blockIdx.x * 256 + threadIdx.x;  // b*HW + g, total B_*HW_ = 100352
    int b = id / HW_;
    int g = id - b * HW_;
    float m = -INFINITY, s = 0.f;
    for (int ck = 0; ck < NCHUNK; ++ck) {
        m = fmaxf(m, P3p[(((size_t)(b * NCHUNK + ck)) * 2 + 0) * HW_ + g]);
        s += P3p[(((size_t)(b * NCHUNK + ck)) * 2 + 1) * HW_ + g];
    }
    P3[((size_t)b * 2 + 0) * HW_ + g] = m;
    P3[((size_t)b * 2 + 1) * HW_ + g] = s * (1.f / 256.f);
}

// ---------------- Kernel C: 7x7 conv (2ch -> 1ch, pad 3) + BN + sigmoid ----------------
// Z: [B][2][A][D], S: [B][A][D]. grid: (ceil(A*D/256), B)
__global__ __launch_bounds__(256) void conv_bn_sig(const float* __restrict__ Z,
                                                   const float* __restrict__ wv,
                                                   const float* __restrict__ gamma,
                                                   const float* __restrict__ beta,
                                                   const float* __restrict__ mean,
                                                   const float* __restrict__ var,
                                                   int k, int A, int D,
                                                   float* __restrict__ S) {
    __shared__ float wl[98];
    const int t = threadIdx.x;
    if (t < 98) wl[t] = wv[t];
    __syncthreads();

    const int b = blockIdx.y;
    const int AD = A * D;
    const int idx = blockIdx.x * 256 + t;
    if (idx >= AD) return;
    const int a = idx / D;
    const int d = idx - a * D;
    const float* Z0 = Z + (size_t)b * 2 * AD;

    float acc = 0.f;
#pragma unroll
    for (int i = 0; i < 2; ++i) {
#pragma unroll
        for (int dy = 0; dy < 7; ++dy) {
            int aa = a + dy - 3;
            if (aa < 0 || aa >= A) continue;
#pragma unroll
            for (int dx = 0; dx < 7; ++dx) {
                int dd = d + dx - 3;
                if (dd < 0 || dd >= D) continue;
                acc += Z0[(size_t)i * AD + aa * D + dd] * wl[i * 49 + dy * 7 + dx];
            }
        }
    }
    float y = (acc - mean[k]) * rsqrtf(var[k] + 1e-5f) * gamma[k] + beta[k];
    S[(size_t)b * AD + idx] = 1.f / (1.f + expf(-y));
}

// ---------------- Kernel D: out = x * (s1 + s2 + s3) / 3 ----------------
// float4 over w. grid: B*C*H*W/4/256 = 25088 blocks exactly.
__global__ __launch_bounds__(256) void final_mul(const float* __restrict__ x,
                                                 const float* __restrict__ s1,  // [B][C][W]
                                                 const float* __restrict__ s2,  // [B][H][C]
                                                 const float* __restrict__ s3,  // [B][H][W]
                                                 float* __restrict__ out) {
    const int vid = blockIdx.x * 256 + threadIdx.x;  // vec4 id
    const int p = vid / 784;        // plane = b*256+c  (784 = 3136/4)
    const int r = vid - p * 784;
    const int h = r / 14;           // 14 = 56/4
    const int w4 = (r - h * 14) << 2;
    const int b = p >> 8;
    const int c = p & 255;

    const size_t xoff = (size_t)p * HW_ + h * 56 + w4;
    const float4 xv = *(const float4*)(x + xoff);
    const float4 s1v = *(const float4*)(s1 + ((size_t)(b * C_ + c)) * W_ + w4);
    const float s2s = s2[((size_t)b * H_ + h) * C_ + c];
    const float4 s3v = *(const float4*)(s3 + ((size_t)b * H_ + h) * W_ + w4);

    float4 o;
    o.x = xv.x * (s1v.x + s2s + s3v.x) * (1.f / 3.f);
    o.y = xv.y * (s1v.y + s2s + s3v.y) * (1.f / 3.f);
    o.z = xv.z * (s1v.z + s2s + s3v.z) * (1.f / 3.f);
    o.w = xv.w * (s1v.w + s2s + s3v.w) * (1.f / 3.f);
    *(float4*)(out + xoff) = o;
}

extern "C" void kernel_launch(void* const* d_in, const int* in_sizes, int n_in,
                              void* d_out, int out_size, void* d_ws, size_t ws_size,
                              hipStream_t stream) {
    const float* x = (const float*)d_in[0];
    const float* w_ch = (const float*)d_in[1];
    const float* w_cw = (const float*)d_in[2];
    const float* w_hw = (const float*)d_in[3];
    const float* gamma = (const float*)d_in[4];
    const float* beta = (const float*)d_in[5];
    const float* mean = (const float*)d_in[6];
    const float* var = (const float*)d_in[7];
    float* out = (float*)d_out;

    float* ws = (float*)d_ws;
    // workspace layout (floats)
    float* P1 = ws;                       // [B][2][C][W]  = 917504
    float* P2 = P1 + 917504;              // [B][2][H][C]  = 917504
    float* P3p = P2 + 917504;             // [B][16][2][HW] = 3211264
    float* P3 = P3p + 3211264;            // [B][2][HW]    = 200704
    float* s1 = P3 + 200704;              // [B][C][W]     = 458752
    float* s2 = s1 + 458752;              // [B][H][C]     = 458752
    float* s3 = s2 + 458752;              // [B][H][W]     = 100352
    // total 6,264,832 floats = 25.06 MB

    pool_kernel<<<B_ * NCHUNK, 256, 0, stream>>>(x, P1, P2, P3p);
    p3_reduce<<<(B_ * HW_) / 256, 256, 0, stream>>>(P3p, P3);

    // branch 1: spatial (C,W) -> s1[b][c][w]
    conv_bn_sig<<<dim3((C_ * W_ + 255) / 256, B_), 256, 0, stream>>>(
        P1, w_ch, gamma, beta, mean, var, 0, C_, W_, s1);
    // branch 2: spatial (H,C) -> s2[b][h][c]
    conv_bn_sig<<<dim3((H_ * C_ + 255) / 256, B_), 256, 0, stream>>>(
        P2, w_cw, gamma, beta, mean, var, 1, H_, C_, s2);
    // branch 3: spatial (H,W) -> s3[b][h][w]
    conv_bn_sig<<<dim3((H_ * W_ + 255) / 256, B_), 256, 0, stream>>>(
        P3, w_hw, gamma, beta, mean, var, 2, H_, W_, s3);

    final_mul<<<(B_ * C_ * HW_) / 4 / 256, 256, 0, stream>>>(x, s1, s2, s3, out);
}

// Round 2
// 296.766 us; speedup vs baseline: 1.4861x; 1.4861x over previous
//
#include <hip/hip_runtime.h>
#include <math.h>

// TripletAttention. x:[32,256,56,56] f32.
// out[b,c,h,w] = x * (s1[b,c,w] + s2[b,h,c] + s3[b,h,w]) / 3

#define B_ 32
#define C_ 256
#define H_ 56
#define W_ 56
#define HW_ 3136
#define LDSW 60  // padded LDS row stride (words); 60%4==0 keeps float4 stores aligned

// ---------------- Kernel A: per-plane pools ----------------
// grid = B*C = 8192 blocks, 256 threads. One plane per block.
// row pool (over w) -> P2[b][2][h][c] ; col pool (over h) -> P1[b][2][c][w]
__global__ __launch_bounds__(256) void pool_hw(const float* __restrict__ x,
                                               float* __restrict__ P1,
                                               float* __restrict__ P2) {
    __shared__ float sm[H_ * LDSW];
    const int t = threadIdx.x;
    const int b = blockIdx.x >> 8;
    const int c = blockIdx.x & 255;
    const float* src = x + (size_t)blockIdx.x * HW_;

    // stage: 784 float4s. threads load t, t+256, t+512 (+ t+768 for t<16)
    float4 v0 = ((const float4*)src)[t];
    float4 v1 = ((const float4*)src)[t + 256];
    float4 v2 = ((const float4*)src)[t + 512];
    float4 v3 = (t < 16) ? ((const float4*)src)[t + 768] : make_float4(0, 0, 0, 0);

    {
        int h0 = t / 14, w0 = (t - h0 * 14) * 4;
        *(float4*)&sm[h0 * LDSW + w0] = v0;
        int v = t + 256; int h1 = v / 14, w1 = (v - h1 * 14) * 4;
        *(float4*)&sm[h1 * LDSW + w1] = v1;
        v = t + 512; int h2 = v / 14, w2 = (v - h2 * 14) * 4;
        *(float4*)&sm[h2 * LDSW + w2] = v2;
        if (t < 16) {
            v = t + 768; int h3 = v / 14, w3 = (v - h3 * 14) * 4;
            *(float4*)&sm[h3 * LDSW + w3] = v3;
        }
    }
    __syncthreads();

    if (t < 224) {
        const int q = t & 3;
        // ---- row phase: reduce over w for row h = t>>2 ; w = q + 4*j (2-way banks)
        {
            const int h = t >> 2;
            float m = -INFINITY, s = 0.f;
#pragma unroll
            for (int j = 0; j < 14; ++j) {
                float v = sm[h * LDSW + q + 4 * j];
                m = fmaxf(m, v); s += v;
            }
            m = fmaxf(m, __shfl_down(m, 1)); s += __shfl_down(s, 1);
            m = fmaxf(m, __shfl_down(m, 2)); s += __shfl_down(s, 2);
            if (q == 0) {
                P2[(((size_t)b * 2 + 0) * H_ + h) * C_ + c] = m;
                P2[(((size_t)b * 2 + 1) * H_ + h) * C_ + c] = s * (1.f / 56.f);
            }
        }
        // ---- col phase: reduce over h for col w = t>>2 ; h = q*14 + j (2-way banks)
        {
            const int w = t >> 2;
            float m = -INFINITY, s = 0.f;
#pragma unroll
            for (int j = 0; j < 14; ++j) {
                float v = sm[(q * 14 + j) * LDSW + w];
                m = fmaxf(m, v); s += v;
            }
            m = fmaxf(m, __shfl_down(m, 1)); s += __shfl_down(s, 1);
            m = fmaxf(m, __shfl_down(m, 2)); s += __shfl_down(s, 2);
            if (q == 0) {
                P1[(((size_t)b * 2 + 0) * C_ + c) * W_ + w] = m;
                P1[(((size_t)b * 2 + 1) * C_ + c) * W_ + w] = s * (1.f / 56.f);
            }
        }
    }
}

// ---------------- Kernel B: pool over c -> P3[b][2][HW] ----------------
// grid = B * 49 blocks, 256 threads. Each block: 64 hw positions x all 256 c.
__global__ __launch_bounds__(256) void pool_c(const float* __restrict__ x,
                                              float* __restrict__ P3) {
    __shared__ float lm[4][64], ls[4][64];
    const int t = threadIdx.x;
    const int lane = t & 63, wv = t >> 6;
    const int b = blockIdx.x / 49;
    const int tile = blockIdx.x - b * 49;
    const int hw = tile * 64 + lane;
    const float* src = x + (size_t)b * C_ * HW_ + hw;

    float m = -INFINITY, s = 0.f;
#pragma unroll 4
    for (int i = 0; i < 64; ++i) {
        float v = src[(size_t)(wv * 64 + i) * HW_];
        m = fmaxf(m, v); s += v;
    }
    lm[wv][lane] = m; ls[wv][lane] = s;
    __syncthreads();
    if (wv == 0) {
#pragma unroll
        for (int k = 1; k < 4; ++k) { m = fmaxf(m, lm[k][lane]); s += ls[k][lane]; }
        P3[((size_t)b * 2 + 0) * HW_ + hw] = m;
        P3[((size_t)b * 2 + 1) * HW_ + hw] = s * (1.f / 256.f);
    }
}

// ---------------- Kernel C: 7x7 conv (2ch -> 1ch, pad 3) + BN + sigmoid ----------------
__global__ __launch_bounds__(256) void conv_bn_sig(const float* __restrict__ Z,
                                                   const float* __restrict__ wv,
                                                   const float* __restrict__ gamma,
                                                   const float* __restrict__ beta,
                                                   const float* __restrict__ mean,
                                                   const float* __restrict__ var,
                                                   int k, int A, int D,
                                                   float* __restrict__ S) {
    __shared__ float wl[98];
    const int t = threadIdx.x;
    if (t < 98) wl[t] = wv[t];
    __syncthreads();

    const int b = blockIdx.y;
    const int AD = A * D;
    const int idx = blockIdx.x * 256 + t;
    if (idx >= AD) return;
    const int a = idx / D;
    const int d = idx - a * D;
    const float* Z0 = Z + (size_t)b * 2 * AD;

    float acc = 0.f;
#pragma unroll
    for (int i = 0; i < 2; ++i) {
#pragma unroll
        for (int dy = 0; dy < 7; ++dy) {
            int aa = a + dy - 3;
            if (aa < 0 || aa >= A) continue;
#pragma unroll
            for (int dx = 0; dx < 7; ++dx) {
                int dd = d + dx - 3;
                if (dd < 0 || dd >= D) continue;
                acc += Z0[(size_t)i * AD + aa * D + dd] * wl[i * 49 + dy * 7 + dx];
            }
        }
    }
    float y = (acc - mean[k]) * rsqrtf(var[k] + 1e-5f) * gamma[k] + beta[k];
    S[(size_t)b * AD + idx] = 1.f / (1.f + expf(-y));
}

// ---------------- Kernel D: out = x * (s1 + s2 + s3) / 3 ----------------
__global__ __launch_bounds__(256) void final_mul(const float* __restrict__ x,
                                                 const float* __restrict__ s1,  // [B][C][W]
                                                 const float* __restrict__ s2,  // [B][H][C]
                                                 const float* __restrict__ s3,  // [B][H][W]
                                                 float* __restrict__ out) {
    const int vid = blockIdx.x * 256 + threadIdx.x;
    const int p = vid / 784;
    const int r = vid - p * 784;
    const int h = r / 14;
    const int w4 = (r - h * 14) << 2;
    const int b = p >> 8;
    const int c = p & 255;

    const size_t xoff = (size_t)p * HW_ + h * 56 + w4;
    const float4 xv = *(const float4*)(x + xoff);
    const float4 s1v = *(const float4*)(s1 + ((size_t)(b * C_ + c)) * W_ + w4);
    const float s2s = s2[((size_t)b * H_ + h) * C_ + c];
    const float4 s3v = *(const float4*)(s3 + ((size_t)b * H_ + h) * W_ + w4);

    float4 o;
    o.x = xv.x * (s1v.x + s2s + s3v.x) * (1.f / 3.f);
    o.y = xv.y * (s1v.y + s2s + s3v.y) * (1.f / 3.f);
    o.z = xv.z * (s1v.z + s2s + s3v.z) * (1.f / 3.f);
    o.w = xv.w * (s1v.w + s2s + s3v.w) * (1.f / 3.f);
    *(float4*)(out + xoff) = o;
}

extern "C" void kernel_launch(void* const* d_in, const int* in_sizes, int n_in,
                              void* d_out, int out_size, void* d_ws, size_t ws_size,
                              hipStream_t stream) {
    const float* x = (const float*)d_in[0];
    const float* w_ch = (const float*)d_in[1];
    const float* w_cw = (const float*)d_in[2];
    const float* w_hw = (const float*)d_in[3];
    const float* gamma = (const float*)d_in[4];
    const float* beta = (const float*)d_in[5];
    const float* mean = (const float*)d_in[6];
    const float* var = (const float*)d_in[7];
    float* out = (float*)d_out;

    float* ws = (float*)d_ws;
    float* P1 = ws;             // [B][2][C][W]  = 917504
    float* P2 = P1 + 917504;    // [B][2][H][C]  = 917504
    float* P3 = P2 + 917504;    // [B][2][HW]    = 200704
    float* s1 = P3 + 200704;    // [B][C][W]     = 458752
    float* s2 = s1 + 458752;    // [B][H][C]     = 458752
    float* s3 = s2 + 458752;    // [B][HW]       = 100352
    // total ~12.2 MB

    pool_hw<<<B_ * C_, 256, 0, stream>>>(x, P1, P2);
    pool_c<<<B_ * 49, 256, 0, stream>>>(x, P3);

    conv_bn_sig<<<dim3((C_ * W_ + 255) / 256, B_), 256, 0, stream>>>(
        P1, w_ch, gamma, beta, mean, var, 0, C_, W_, s1);
    conv_bn_sig<<<dim3((H_ * C_ + 255) / 256, B_), 256, 0, stream>>>(
        P2, w_cw, gamma, beta, mean, var, 1, H_, C_, s2);
    conv_bn_sig<<<dim3((H_ * W_ + 255) / 256, B_), 256, 0, stream>>>(
        P3, w_hw, gamma, beta, mean, var, 2, H_, W_, s3);

    final_mul<<<(B_ * C_ * HW_) / 4 / 256, 256, 0, stream>>>(x, s1, s2, s3, out);
}

// Round 3
// 278.613 us; speedup vs baseline: 1.5830x; 1.0652x over previous
//
#include <hip/hip_runtime.h>
#include <math.h>

// TripletAttention. x:[32,256,56,56] f32.
// out[b,c,h,w] = x * (s1[b,c,w] + s2[b,h,c] + s3[b,h,w]) / 3

#define B_ 32
#define C_ 256
#define H_ 56
#define W_ 56
#define HW_ 3136
#define LDSW 60        // padded LDS row stride (words); %4==0 keeps float4 stores aligned
#define NPOOLHW (B_ * C_)   // 8192 blocks: per-plane row/col pools
#define NPOOLC (B_ * 49)    // 1568 blocks: c-pool tiles

// ---------------- Kernel 1: all pools in one dispatch ----------------
__global__ __launch_bounds__(256) void pool_all(const float* __restrict__ x,
                                                float* __restrict__ P1,   // [B][2][C][W]
                                                float* __restrict__ P2,   // [B][2][H][C]
                                                float* __restrict__ P3) { // [B][2][HW]
    __shared__ float sm[H_ * LDSW];
    const int t = threadIdx.x;
    const int bid = blockIdx.x;

    if (bid < NPOOLHW) {
        // ======== per-plane pools: row (over w) -> P2, col (over h) -> P1 ========
        const int b = bid >> 8;
        const int c = bid & 255;
        const float* src = x + (size_t)bid * HW_;

        float4 v0 = ((const float4*)src)[t];
        float4 v1 = ((const float4*)src)[t + 256];
        float4 v2 = ((const float4*)src)[t + 512];
        float4 v3 = (t < 16) ? ((const float4*)src)[t + 768] : make_float4(0, 0, 0, 0);
        {
            int h0 = t / 14, w0 = (t - h0 * 14) * 4;
            *(float4*)&sm[h0 * LDSW + w0] = v0;
            int v = t + 256; int h1 = v / 14, w1 = (v - h1 * 14) * 4;
            *(float4*)&sm[h1 * LDSW + w1] = v1;
            v = t + 512; int h2 = v / 14, w2 = (v - h2 * 14) * 4;
            *(float4*)&sm[h2 * LDSW + w2] = v2;
            if (t < 16) {
                v = t + 768; int h3 = v / 14, w3 = (v - h3 * 14) * 4;
                *(float4*)&sm[h3 * LDSW + w3] = v3;
            }
        }
        __syncthreads();

        if (t < 224) {
            const int q = t & 3;
            {   // row phase: reduce over w for row h = t>>2 ; w = q+4j (2-way banks, free)
                const int h = t >> 2;
                float m = -INFINITY, s = 0.f;
#pragma unroll
                for (int j = 0; j < 14; ++j) {
                    float v = sm[h * LDSW + q + 4 * j];
                    m = fmaxf(m, v); s += v;
                }
                m = fmaxf(m, __shfl_down(m, 1)); s += __shfl_down(s, 1);
                m = fmaxf(m, __shfl_down(m, 2)); s += __shfl_down(s, 2);
                if (q == 0) {
                    P2[(((size_t)b * 2 + 0) * H_ + h) * C_ + c] = m;
                    P2[(((size_t)b * 2 + 1) * H_ + h) * C_ + c] = s * (1.f / 56.f);
                }
            }
            {   // col phase: reduce over h for col w = t>>2 ; h = q*14+j (2-way banks)
                const int w = t >> 2;
                float m = -INFINITY, s = 0.f;
#pragma unroll
                for (int j = 0; j < 14; ++j) {
                    float v = sm[(q * 14 + j) * LDSW + w];
                    m = fmaxf(m, v); s += v;
                }
                m = fmaxf(m, __shfl_down(m, 1)); s += __shfl_down(s, 1);
                m = fmaxf(m, __shfl_down(m, 2)); s += __shfl_down(s, 2);
                if (q == 0) {
                    P1[(((size_t)b * 2 + 0) * C_ + c) * W_ + w] = m;
                    P1[(((size_t)b * 2 + 1) * C_ + c) * W_ + w] = s * (1.f / 56.f);
                }
            }
        }
    } else {
        // ======== c-pool: 64 hw positions x 256 c per block ========
        float* lm = sm;          // [4][64]
        float* ls = sm + 256;    // [4][64]
        const int id = bid - NPOOLHW;
        const int lane = t & 63, wv = t >> 6;
        const int b = id / 49;
        const int tile = id - b * 49;
        const int hw = tile * 64 + lane;
        const float* src = x + (size_t)b * C_ * HW_ + hw;

        float m = -INFINITY, s = 0.f;
#pragma unroll 8
        for (int i = 0; i < 64; ++i) {
            float v = src[(size_t)(wv * 64 + i) * HW_];
            m = fmaxf(m, v); s += v;
        }
        lm[wv * 64 + lane] = m; ls[wv * 64 + lane] = s;
        __syncthreads();
        if (wv == 0) {
#pragma unroll
            for (int k = 1; k < 4; ++k) {
                m = fmaxf(m, lm[k * 64 + lane]); s += ls[k * 64 + lane];
            }
            P3[((size_t)b * 2 + 0) * HW_ + hw] = m;
            P3[((size_t)b * 2 + 1) * HW_ + hw] = s * (1.f / 256.f);
        }
    }
}

// ---------------- Kernel 2: all three 7x7 conv+BN+sigmoid in one dispatch ----------------
// grid: (56, B, 3). branch k = blockIdx.z.
__global__ __launch_bounds__(256) void conv_all(const float* __restrict__ P1,
                                                const float* __restrict__ P2,
                                                const float* __restrict__ P3,
                                                const float* __restrict__ w_ch,
                                                const float* __restrict__ w_cw,
                                                const float* __restrict__ w_hw,
                                                const float* __restrict__ gamma,
                                                const float* __restrict__ beta,
                                                const float* __restrict__ mean,
                                                const float* __restrict__ var,
                                                float* __restrict__ s1,
                                                float* __restrict__ s2,
                                                float* __restrict__ s3) {
    const int k = blockIdx.z;
    const float* Z; const float* wsrc; float* S; int A, D;
    if (k == 0)      { Z = P1; wsrc = w_ch; S = s1; A = C_; D = W_; }
    else if (k == 1) { Z = P2; wsrc = w_cw; S = s2; A = H_; D = C_; }
    else             { Z = P3; wsrc = w_hw; S = s3; A = H_; D = W_; }

    __shared__ float wl[98];
    const int t = threadIdx.x;
    if (t < 98) wl[t] = wsrc[t];
    __syncthreads();

    const int b = blockIdx.y;
    const int AD = A * D;
    const int idx = blockIdx.x * 256 + t;
    if (idx >= AD) return;
    const int a = idx / D;
    const int d = idx - a * D;
    const float* Z0 = Z + (size_t)b * 2 * AD;

    float acc = 0.f;
#pragma unroll
    for (int i = 0; i < 2; ++i) {
#pragma unroll
        for (int dy = 0; dy < 7; ++dy) {
            int aa = a + dy - 3;
            if (aa < 0 || aa >= A) continue;
#pragma unroll
            for (int dx = 0; dx < 7; ++dx) {
                int dd = d + dx - 3;
                if (dd < 0 || dd >= D) continue;
                acc += Z0[(size_t)i * AD + aa * D + dd] * wl[i * 49 + dy * 7 + dx];
            }
        }
    }
    float y = (acc - mean[k]) * rsqrtf(var[k] + 1e-5f) * gamma[k] + beta[k];
    S[(size_t)b * AD + idx] = 1.f / (1.f + expf(-y));
}

// ---------------- Kernel 3: out = x * (s1 + s2 + s3) / 3 ----------------
__global__ __launch_bounds__(256) void final_mul(const float* __restrict__ x,
                                                 const float* __restrict__ s1,  // [B][C][W]
                                                 const float* __restrict__ s2,  // [B][H][C]
                                                 const float* __restrict__ s3,  // [B][H][W]
                                                 float* __restrict__ out) {
    const int vid = blockIdx.x * 256 + threadIdx.x;
    const int p = vid / 784;
    const int r = vid - p * 784;
    const int h = r / 14;
    const int w4 = (r - h * 14) << 2;
    const int b = p >> 8;
    const int c = p & 255;

    const size_t xoff = (size_t)p * HW_ + h * 56 + w4;
    const float4 xv = *(const float4*)(x + xoff);
    const float4 s1v = *(const float4*)(s1 + ((size_t)(b * C_ + c)) * W_ + w4);
    const float s2s = s2[((size_t)b * H_ + h) * C_ + c];
    const float4 s3v = *(const float4*)(s3 + ((size_t)b * H_ + h) * W_ + w4);

    float4 o;
    o.x = xv.x * (s1v.x + s2s + s3v.x) * (1.f / 3.f);
    o.y = xv.y * (s1v.y + s2s + s3v.y) * (1.f / 3.f);
    o.z = xv.z * (s1v.z + s2s + s3v.z) * (1.f / 3.f);
    o.w = xv.w * (s1v.w + s2s + s3v.w) * (1.f / 3.f);
    *(float4*)(out + xoff) = o;
}

extern "C" void kernel_launch(void* const* d_in, const int* in_sizes, int n_in,
                              void* d_out, int out_size, void* d_ws, size_t ws_size,
                              hipStream_t stream) {
    const float* x = (const float*)d_in[0];
    const float* w_ch = (const float*)d_in[1];
    const float* w_cw = (const float*)d_in[2];
    const float* w_hw = (const float*)d_in[3];
    const float* gamma = (const float*)d_in[4];
    const float* beta = (const float*)d_in[5];
    const float* mean = (const float*)d_in[6];
    const float* var = (const float*)d_in[7];
    float* out = (float*)d_out;

    float* ws = (float*)d_ws;
    float* P1 = ws;             // [B][2][C][W]  = 917504
    float* P2 = P1 + 917504;    // [B][2][H][C]  = 917504
    float* P3 = P2 + 917504;    // [B][2][HW]    = 200704
    float* s1 = P3 + 200704;    // [B][C][W]     = 458752
    float* s2 = s1 + 458752;    // [B][H][C]     = 458752
    float* s3 = s2 + 458752;    // [B][HW]       = 100352
    // total ~12.2 MB

    pool_all<<<NPOOLHW + NPOOLC, 256, 0, stream>>>(x, P1, P2, P3);
    conv_all<<<dim3(56, B_, 3), 256, 0, stream>>>(P1, P2, P3, w_ch, w_cw, w_hw,
                                                  gamma, beta, mean, var, s1, s2, s3);
    final_mul<<<(B_ * C_ * HW_) / 4 / 256, 256, 0, stream>>>(x, s1, s2, s3, out);
}

// Round 4
// 264.140 us; speedup vs baseline: 1.6697x; 1.0548x over previous
//
#include <hip/hip_runtime.h>
#include <math.h>

// TripletAttention. x:[32,256,56,56] f32.
// out[b,c,h,w] = x * (s1[b,c,w] + s2[b,h,c] + s3[b,h,w]) / 3

#define B_ 32
#define C_ 256
#define H_ 56
#define W_ 56
#define HW_ 3136
#define LDSW 60              // padded LDS row stride (words); %4==0 keeps float4 stores aligned
#define NPOOLC (B_ * 49 * 2) // 3136 c-pool blocks (2 chunks of 128 c), dispatched FIRST
#define NPOOLHW (B_ * C_)    // 8192 per-plane row/col pool blocks

// ---------------- Kernel 1: all pools in one dispatch ----------------
// c-pool blocks first (long-latency strided loads overlap the hw-pool stream).
__global__ __launch_bounds__(256) void pool_all(const float* __restrict__ x,
                                                float* __restrict__ P1,    // [B][2][C][W]
                                                float* __restrict__ P2,    // [B][2][H][C]
                                                float* __restrict__ P3p) { // [B][2chunk][2][HW]
    __shared__ float sm[H_ * LDSW];
    const int t = threadIdx.x;
    const int bid = blockIdx.x;

    if (bid < NPOOLC) {
        // ======== c-pool: 64 hw positions x 128 c per block ========
        const int chunk = bid & 1;
        const int rest = bid >> 1;
        const int b = rest / 49;
        const int tile = rest - b * 49;
        const int lane = t & 63, wv = t >> 6;
        const int hw = tile * 64 + lane;
        const float* src = x + (size_t)b * C_ * HW_ + (size_t)(chunk * 128 + wv * 32) * HW_ + hw;

        float m0 = -INFINITY, m1 = -INFINITY, s0 = 0.f, s1a = 0.f;
#pragma unroll
        for (int i = 0; i < 16; ++i) {
            float v0 = src[(size_t)(2 * i) * HW_];
            float v1 = src[(size_t)(2 * i + 1) * HW_];
            m0 = fmaxf(m0, v0); s0 += v0;
            m1 = fmaxf(m1, v1); s1a += v1;
        }
        float m = fmaxf(m0, m1), s = s0 + s1a;

        float* lm = sm;        // [4][64]
        float* ls = sm + 256;  // [4][64]
        lm[wv * 64 + lane] = m; ls[wv * 64 + lane] = s;
        __syncthreads();
        if (wv == 0) {
#pragma unroll
            for (int k = 1; k < 4; ++k) {
                m = fmaxf(m, lm[k * 64 + lane]); s += ls[k * 64 + lane];
            }
            P3p[(((size_t)b * 2 + chunk) * 2 + 0) * HW_ + hw] = m;
            P3p[(((size_t)b * 2 + chunk) * 2 + 1) * HW_ + hw] = s;  // raw sum over 128 c
        }
    } else {
        // ======== per-plane pools: row (over w) -> P2, col (over h) -> P1 ========
        const int bid2 = bid - NPOOLC;
        const int b = bid2 >> 8;
        const int c = bid2 & 255;
        const float* src = x + (size_t)bid2 * HW_;

        float4 v0 = ((const float4*)src)[t];
        float4 v1 = ((const float4*)src)[t + 256];
        float4 v2 = ((const float4*)src)[t + 512];
        float4 v3 = (t < 16) ? ((const float4*)src)[t + 768] : make_float4(0, 0, 0, 0);
        {
            int h0 = t / 14, w0 = (t - h0 * 14) * 4;
            *(float4*)&sm[h0 * LDSW + w0] = v0;
            int v = t + 256; int h1 = v / 14, w1 = (v - h1 * 14) * 4;
            *(float4*)&sm[h1 * LDSW + w1] = v1;
            v = t + 512; int h2 = v / 14, w2 = (v - h2 * 14) * 4;
            *(float4*)&sm[h2 * LDSW + w2] = v2;
            if (t < 16) {
                v = t + 768; int h3 = v / 14, w3 = (v - h3 * 14) * 4;
                *(float4*)&sm[h3 * LDSW + w3] = v3;
            }
        }
        __syncthreads();

        if (t < 224) {
            const int q = t & 3;
            {   // row phase: reduce over w for row h = t>>2 ; w = q+4j (2-way banks, free)
                const int h = t >> 2;
                float m = -INFINITY, s = 0.f;
#pragma unroll
                for (int j = 0; j < 14; ++j) {
                    float v = sm[h * LDSW + q + 4 * j];
                    m = fmaxf(m, v); s += v;
                }
                m = fmaxf(m, __shfl_down(m, 1)); s += __shfl_down(s, 1);
                m = fmaxf(m, __shfl_down(m, 2)); s += __shfl_down(s, 2);
                if (q == 0) {
                    P2[(((size_t)b * 2 + 0) * H_ + h) * C_ + c] = m;
                    P2[(((size_t)b * 2 + 1) * H_ + h) * C_ + c] = s * (1.f / 56.f);
                }
            }
            {   // col phase: reduce over h for col w = t>>2 ; h = q*14+j (2-way banks)
                const int w = t >> 2;
                float m = -INFINITY, s = 0.f;
#pragma unroll
                for (int j = 0; j < 14; ++j) {
                    float v = sm[(q * 14 + j) * LDSW + w];
                    m = fmaxf(m, v); s += v;
                }
                m = fmaxf(m, __shfl_down(m, 1)); s += __shfl_down(s, 1);
                m = fmaxf(m, __shfl_down(m, 2)); s += __shfl_down(s, 2);
                if (q == 0) {
                    P1[(((size_t)b * 2 + 0) * C_ + c) * W_ + w] = m;
                    P1[(((size_t)b * 2 + 1) * C_ + c) * W_ + w] = s * (1.f / 56.f);
                }
            }
        }
    }
}

// ---------------- Kernel 2: all three 7x7 conv+BN+sigmoid in one dispatch ----------------
// grid: (56, B, 3). branch k = blockIdx.z. Branch 2 combines the two c-chunks inline.
__global__ __launch_bounds__(256) void conv_all(const float* __restrict__ P1,
                                                const float* __restrict__ P2,
                                                const float* __restrict__ P3p,
                                                const float* __restrict__ w_ch,
                                                const float* __restrict__ w_cw,
                                                const float* __restrict__ w_hw,
                                                const float* __restrict__ gamma,
                                                const float* __restrict__ beta,
                                                const float* __restrict__ mean,
                                                const float* __restrict__ var,
                                                float* __restrict__ s1,
                                                float* __restrict__ s2,
                                                float* __restrict__ s3) {
    const int k = blockIdx.z;
    const float* Z; const float* wsrc; float* S; int A, D;
    if (k == 0)      { Z = P1;  wsrc = w_ch; S = s1; A = C_; D = W_; }
    else if (k == 1) { Z = P2;  wsrc = w_cw; S = s2; A = H_; D = C_; }
    else             { Z = P3p; wsrc = w_hw; S = s3; A = H_; D = W_; }

    __shared__ float wl[98];
    const int t = threadIdx.x;
    if (t < 98) wl[t] = wsrc[t];
    __syncthreads();

    const int b = blockIdx.y;
    const int AD = A * D;
    const int idx = blockIdx.x * 256 + t;
    if (idx >= AD) return;
    const int a = idx / D;
    const int d = idx - a * D;

    float acc = 0.f;
    if (k < 2) {
        const float* Z0 = Z + (size_t)b * 2 * AD;
#pragma unroll
        for (int dy = 0; dy < 7; ++dy) {
            int aa = a + dy - 3;
            if (aa < 0 || aa >= A) continue;
#pragma unroll
            for (int dx = 0; dx < 7; ++dx) {
                int dd = d + dx - 3;
                if (dd < 0 || dd >= D) continue;
                acc += Z0[aa * D + dd] * wl[dy * 7 + dx]
                     + Z0[AD + aa * D + dd] * wl[49 + dy * 7 + dx];
            }
        }
    } else {
        const float* Zm0 = Z + (((size_t)b * 2 + 0) * 2 + 0) * HW_;
        const float* Zs0 = Z + (((size_t)b * 2 + 0) * 2 + 1) * HW_;
        const float* Zm1 = Z + (((size_t)b * 2 + 1) * 2 + 0) * HW_;
        const float* Zs1 = Z + (((size_t)b * 2 + 1) * 2 + 1) * HW_;
#pragma unroll
        for (int dy = 0; dy < 7; ++dy) {
            int aa = a + dy - 3;
            if (aa < 0 || aa >= A) continue;
#pragma unroll
            for (int dx = 0; dx < 7; ++dx) {
                int dd = d + dx - 3;
                if (dd < 0 || dd >= D) continue;
                int o = aa * D + dd;
                float zmax = fmaxf(Zm0[o], Zm1[o]);
                float zmean = (Zs0[o] + Zs1[o]) * (1.f / 256.f);
                acc += zmax * wl[dy * 7 + dx] + zmean * wl[49 + dy * 7 + dx];
            }
        }
    }
    float y = (acc - mean[k]) * rsqrtf(var[k] + 1e-5f) * gamma[k] + beta[k];
    S[(size_t)b * AD + idx] = 1.f / (1.f + expf(-y));
}

// ---------------- Kernel 3: out = x * (s1 + s2 + s3) / 3 ----------------
__global__ __launch_bounds__(256) void final_mul(const float* __restrict__ x,
                                                 const float* __restrict__ s1,  // [B][C][W]
                                                 const float* __restrict__ s2,  // [B][H][C]
                                                 const float* __restrict__ s3,  // [B][H][W]
                                                 float* __restrict__ out) {
    const int vid = blockIdx.x * 256 + threadIdx.x;
    const int p = vid / 784;
    const int r = vid - p * 784;
    const int h = r / 14;
    const int w4 = (r - h * 14) << 2;
    const int b = p >> 8;
    const int c = p & 255;

    const size_t xoff = (size_t)p * HW_ + h * 56 + w4;
    const float4 xv = *(const float4*)(x + xoff);
    const float4 s1v = *(const float4*)(s1 + ((size_t)(b * C_ + c)) * W_ + w4);
    const float s2s = s2[((size_t)b * H_ + h) * C_ + c];
    const float4 s3v = *(const float4*)(s3 + ((size_t)b * H_ + h) * W_ + w4);

    float4 o;
    o.x = xv.x * (s1v.x + s2s + s3v.x) * (1.f / 3.f);
    o.y = xv.y * (s1v.y + s2s + s3v.y) * (1.f / 3.f);
    o.z = xv.z * (s1v.z + s2s + s3v.z) * (1.f / 3.f);
    o.w = xv.w * (s1v.w + s2s + s3v.w) * (1.f / 3.f);
    *(float4*)(out + xoff) = o;
}

extern "C" void kernel_launch(void* const* d_in, const int* in_sizes, int n_in,
                              void* d_out, int out_size, void* d_ws, size_t ws_size,
                              hipStream_t stream) {
    const float* x = (const float*)d_in[0];
    const float* w_ch = (const float*)d_in[1];
    const float* w_cw = (const float*)d_in[2];
    const float* w_hw = (const float*)d_in[3];
    const float* gamma = (const float*)d_in[4];
    const float* beta = (const float*)d_in[5];
    const float* mean = (const float*)d_in[6];
    const float* var = (const float*)d_in[7];
    float* out = (float*)d_out;

    float* ws = (float*)d_ws;
    float* P1 = ws;             // [B][2][C][W]      = 917504
    float* P2 = P1 + 917504;    // [B][2][H][C]      = 917504
    float* P3p = P2 + 917504;   // [B][2chunk][2][HW] = 401408
    float* s1 = P3p + 401408;   // [B][C][W]         = 458752
    float* s2 = s1 + 458752;    // [B][H][C]         = 458752
    float* s3 = s2 + 458752;    // [B][HW]           = 100352
    // total ~14.5 MB

    pool_all<<<NPOOLC + NPOOLHW, 256, 0, stream>>>(x, P1, P2, P3p);
    conv_all<<<dim3(56, B_, 3), 256, 0, stream>>>(P1, P2, P3p, w_ch, w_cw, w_hw,
                                                  gamma, beta, mean, var, s1, s2, s3);
    final_mul<<<(B_ * C_ * HW_) / 4 / 256, 256, 0, stream>>>(x, s1, s2, s3, out);
}